// Round 10
// baseline (3964.961 us; speedup 1.0000x reference)
//
#include <hip/hip_runtime.h>
#include <cstdint>
#include <cstddef>

typedef _Float16 f16;
typedef _Float16 half4_t __attribute__((ext_vector_type(4)));
typedef _Float16 half8_t __attribute__((ext_vector_type(8)));
typedef float floatx4 __attribute__((ext_vector_type(4)));

// ---------------- fp32 [b][t][d] -> f16 flatm-major [(t*64+b)][d] ----------------
__global__ void cvt_x_tm(const float* __restrict__ in, f16* __restrict__ out, int n4) {
    int i = blockIdx.x * blockDim.x + threadIdx.x;
    int stride = gridDim.x * blockDim.x;
    const float4* in4 = (const float4*)in;
    for (; i < n4; i += stride) {
        float4 v = in4[i];
        int elem = i * 4;
        int d = elem & 511;
        int t = (elem >> 9) & 511;
        int b = elem >> 18;
        half4_t h = {(f16)v.x, (f16)v.y, (f16)v.z, (f16)v.w};
        *(half4_t*)&out[((size_t)t * 64 + b) * 512 + d] = h;
    }
}

// ---------------- plain fp32 -> f16 copy (row-major weights) ----------------
__global__ void cvt_kernel(const float* __restrict__ in, f16* __restrict__ out, int n4) {
    int i = blockIdx.x * blockDim.x + threadIdx.x;
    int stride = gridDim.x * blockDim.x;
    const float4* in4 = (const float4*)in;
    for (; i < n4; i += stride) {
        float4 v = in4[i];
        half4_t h = {(f16)v.x, (f16)v.y, (f16)v.z, (f16)v.w};
        *(half4_t*)&out[(size_t)i * 4] = h;
    }
}

// ---------------- bias sum ----------------
__global__ void bsum_kernel(const float* __restrict__ a, const float* __restrict__ b,
                            float* __restrict__ o) {
    int i = threadIdx.x;
    o[i] = a[i] + b[i];
}

// ---------------- pack W_hh into MFMA A-operand fragments ----------------
// Frag fid = nt*16 + kt (nt = j>>4, kt = k>>5). Lane l = g*16 + (j&15), g = (k>>3)&3,
// e = k&7. wpk f16 elem index = (fid*64 + lane)*8 + e, value W[j][k].
__global__ void packw_frag(const float* __restrict__ W, f16* __restrict__ wpk) {
    int id = blockIdx.x * 256 + threadIdx.x;    // 262144 = 512*512
    int j = id >> 9, k = id & 511;
    int nt = j >> 4, lj = j & 15;
    int kt = k >> 5, g = (k >> 3) & 3, e = k & 7;
    int lane = g * 16 + lj;
    int fid = nt * 16 + kt;
    wpk[((size_t)(fid * 64 + lane)) * 8 + e] = (f16)W[(size_t)j * 512 + k];
}

// ---------------- GEMM: xpk-frag[j, mflat] = W_ih * X^T + bias, raw-fragment output ----
// C[j][mflat] = sum_k Wrows[j][k] * Xtm[mflat][k] + bias[j];  mflat = t*64 + b.
// Output written as raw 16x16 MFMA fragments: quad (e=0..3) of lane l of tile (mt, jt)
// at f16 offset ((mt*32 + jt)*64 + l)*4, value C[jt*16+(l>>4)*4+e][mt*16+(l&15)].
__global__ __launch_bounds__(256) void gemm_frag(const f16* __restrict__ Wrows,
                                                 const f16* __restrict__ Xtm,
                                                 const float* __restrict__ bias,
                                                 f16* __restrict__ xpk) {
    const int bj = blockIdx.x & 3;    // j / 128
    const int bm = blockIdx.x >> 2;   // mflat / 128
    const int tid = threadIdx.x;
    const int w = tid >> 6, l = tid & 63;
    const int wr = w >> 1, wc = w & 1;
    __shared__ f16 As[128 * 32];
    __shared__ f16 Bs[128 * 32];
    floatx4 acc[4][4] = {};
    const int lr = l & 15, lk = (l >> 4) * 8, lq = l >> 4;
    for (int kk = 0; kk < 512; kk += 32) {
        __syncthreads();
        uint4 av[2], bv[2];
#pragma unroll
        for (int s = 0; s < 2; ++s) {
            int chunk = tid + s * 256;
            int row = chunk >> 2;
            int colh = (chunk & 3) * 8;
            av[s] = *(const uint4*)&Wrows[((size_t)(bj * 128 + row)) * 512 + kk + colh];
            bv[s] = *(const uint4*)&Xtm[((size_t)(bm * 128 + row)) * 512 + kk + colh];
        }
#pragma unroll
        for (int s = 0; s < 2; ++s) {
            int chunk = tid + s * 256;
            *(uint4*)&As[chunk * 8] = av[s];
            *(uint4*)&Bs[chunk * 8] = bv[s];
        }
        __syncthreads();
        half8_t af[4], bf[4];
#pragma unroll
        for (int m = 0; m < 4; ++m)
            af[m] = *(const half8_t*)&As[(wr * 64 + m * 16 + lr) * 32 + lk];
#pragma unroll
        for (int n = 0; n < 4; ++n)
            bf[n] = *(const half8_t*)&Bs[(wc * 64 + n * 16 + lr) * 32 + lk];
#pragma unroll
        for (int m = 0; m < 4; ++m)
#pragma unroll
            for (int n = 0; n < 4; ++n)
                acc[m][n] = __builtin_amdgcn_mfma_f32_16x16x32_f16(af[m], bf[n], acc[m][n], 0, 0, 0);
    }
#pragma unroll
    for (int m = 0; m < 4; ++m) {
        float4 bzv = *(const float4*)&bias[bj * 128 + wr * 64 + m * 16 + lq * 4];
#pragma unroll
        for (int n = 0; n < 4; ++n) {
            half4_t q = {(f16)(acc[m][n][0] + bzv.x), (f16)(acc[m][n][1] + bzv.y),
                         (f16)(acc[m][n][2] + bzv.z), (f16)(acc[m][n][3] + bzv.w)};
            size_t jt = bj * 8 + wr * 4 + m;
            size_t mt = bm * 8 + wc * 4 + n;
            *(half4_t*)&xpk[((mt * 32 + jt) * 64 + l) * 4] = q;
        }
    }
}

// ---------------- MFMA persistent recurrence ----------------
// 4 blocks x 16 batch rows. Per step: D[j, batch] = sum_kt Wfrag x hfrag + xpk-quad.
// W: 64 named half8 fragments (256 dwords) -> AGPR-resident, consumed natively by MFMA.
#define FOR_KT(M, j) M(j,0) M(j,1) M(j,2) M(j,3) M(j,4) M(j,5) M(j,6) M(j,7) \
                     M(j,8) M(j,9) M(j,10) M(j,11) M(j,12) M(j,13) M(j,14) M(j,15)
#define FOR_JL(M) FOR_KT(M,0) FOR_KT(M,1) FOR_KT(M,2) FOR_KT(M,3)

#define DECLF(j,k) half8_t Wf##j##_##k;
#define LOADF(j,k) Wf##j##_##k = *(const half8_t*)&wpk[((size_t)(((w*4+(j))*16 + (k))*64 + l)) * 8];
#define MF(j,k) acc##j = __builtin_amdgcn_mfma_f32_16x16x32_f16(Wf##j##_##k, hf, acc##j, 0, 0, 0);
#define STEP_KT(k) { half8_t hf = *(const half8_t*)(hbase + (k) * 32); \
                     MF(0,k) MF(1,k) MF(2,k) MF(3,k) }
#define ALL_KT STEP_KT(0) STEP_KT(1) STEP_KT(2) STEP_KT(3) STEP_KT(4) STEP_KT(5) \
               STEP_KT(6) STEP_KT(7) STEP_KT(8) STEP_KT(9) STEP_KT(10) STEP_KT(11) \
               STEP_KT(12) STEP_KT(13) STEP_KT(14) STEP_KT(15)

#define ROWF 520   // hh row stride in f16 (512 + 8 pad): 16B-aligned, bank-floor reads

__device__ __forceinline__ floatx4 quad2f(uint2 q) {
    half4_t h = __builtin_bit_cast(half4_t, q);
    floatx4 r = {(float)h[0], (float)h[1], (float)h[2], (float)h[3]};
    return r;
}

#define TANH4(j) { \
    floatx4 aa = acc##j; \
    float e0 = __expf(2.0f * aa[0]), e1 = __expf(2.0f * aa[1]); \
    float e2 = __expf(2.0f * aa[2]), e3 = __expf(2.0f * aa[3]); \
    half4_t hv = {(f16)(1.0f - 2.0f / (1.0f + e0)), (f16)(1.0f - 2.0f / (1.0f + e1)), \
                  (f16)(1.0f - 2.0f / (1.0f + e2)), (f16)(1.0f - 2.0f / (1.0f + e3))}; \
    *(half4_t*)&hhn[w * 64 + (j) * 16 + g4] = hv; }

__global__ __launch_bounds__(512)
__attribute__((amdgpu_waves_per_eu(2, 2)))
void rnn_mfma(const f16* __restrict__ xpk, const f16* __restrict__ wpk,
              f16* __restrict__ hexp,   // flatm-major export (layer0) or nullptr
              f16* __restrict__ hlast,  // [row][512] final-h (layer1) or nullptr
              int store_all) {
    const int bi = blockIdx.x;          // rows 16*bi .. 16*bi+15
    const int tid = threadIdx.x;
    const int w = tid >> 6, l = tid & 63;
    const int r = tid >> 5, chunk = tid & 31;   // export mapping
    __shared__ alignas(16) f16 hh[2][16 * ROWF];

    FOR_JL(DECLF)
    FOR_JL(LOADF)
    for (int i = tid; i < 16 * ROWF; i += 512) hh[0][i] = (f16)0.f;
    __syncthreads();

    // per-lane xpk quad base: tile (mt = t*4+bi, jt = w*4+jl), lane l
    const f16* xq_base = xpk + ((size_t)bi * 32 + w * 4) * 64 * 4 + (size_t)l * 4;
    // xq offset for (t, jl): ((t*4)*32 + jl)*64*4 = t*32768 + jl*256
    uint2 xq0 = *(const uint2*)(xq_base + 0 * 256);
    uint2 xq1 = *(const uint2*)(xq_base + 1 * 256);
    uint2 xq2 = *(const uint2*)(xq_base + 2 * 256);
    uint2 xq3 = *(const uint2*)(xq_base + 3 * 256);

    const int g4 = (l >> 4) * 4;
    int p = 0;
    for (int t = 0; t < 512; ++t) {
        floatx4 acc0 = quad2f(xq0), acc1 = quad2f(xq1);
        floatx4 acc2 = quad2f(xq2), acc3 = quad2f(xq3);
        if (t + 1 < 512) {
            const f16* nb = xq_base + (size_t)(t + 1) * 32768;
            xq0 = *(const uint2*)(nb + 0 * 256);
            xq1 = *(const uint2*)(nb + 1 * 256);
            xq2 = *(const uint2*)(nb + 2 * 256);
            xq3 = *(const uint2*)(nb + 3 * 256);
        }
        // export previous h (stable since last barrier) while MFMA runs
        if (store_all && t > 0) {
            const f16* src = &hh[p][r * ROWF + chunk * 16];
            uint4 v0 = *(const uint4*)src;
            uint4 v1 = *(const uint4*)(src + 8);
            f16* dst = hexp + (((size_t)(t - 1) * 64) + 16 * bi + r) * 512 + chunk * 16;
            *(uint4*)dst = v0;
            *(uint4*)(dst + 8) = v1;
        }

        const f16* hbase = &hh[p][(l & 15) * ROWF + (l >> 4) * 8];
        ALL_KT

        f16* hhn = &hh[p ^ 1][(l & 15) * ROWF];
        TANH4(0) TANH4(1) TANH4(2) TANH4(3)
        __syncthreads();
        p ^= 1;
    }
    // final h export
    {
        const f16* src = &hh[p][r * ROWF + chunk * 16];
        uint4 v0 = *(const uint4*)src;
        uint4 v1 = *(const uint4*)(src + 8);
        if (store_all) {
            f16* dst = hexp + (((size_t)511 * 64) + 16 * bi + r) * 512 + chunk * 16;
            *(uint4*)dst = v0;
            *(uint4*)(dst + 8) = v1;
        } else if (hlast) {
            f16* dst = hlast + (size_t)(16 * bi + r) * 512 + chunk * 16;
            *(uint4*)dst = v0;
            *(uint4*)(dst + 8) = v1;
        }
    }
}

// ---------------- final FC ----------------
__global__ __launch_bounds__(512) void fc_kernel(const f16* __restrict__ h1,
                                                 const float* __restrict__ Wfc,
                                                 const float* __restrict__ bfc,
                                                 float* __restrict__ out) {
    int b = blockIdx.x, tid = threadIdx.x;
    __shared__ float red[8];
    float v = (float)h1[(size_t)b * 512 + tid] * Wfc[tid];
#pragma unroll
    for (int off = 32; off > 0; off >>= 1) v += __shfl_down(v, off, 64);
    if ((tid & 63) == 0) red[tid >> 6] = v;
    __syncthreads();
    if (tid == 0) {
        float s = bfc[0];
#pragma unroll
        for (int g = 0; g < 8; ++g) s += red[g];
        out[b] = s;
    }
}

extern "C" void kernel_launch(void* const* d_in, const int* in_sizes, int n_in,
                              void* d_out, int out_size, void* d_ws, size_t ws_size,
                              hipStream_t stream) {
    const float* x    = (const float*)d_in[0];
    const float* Wih0 = (const float*)d_in[1];
    const float* Whh0 = (const float*)d_in[2];
    const float* bih0 = (const float*)d_in[3];
    const float* bhh0 = (const float*)d_in[4];
    const float* Wih1 = (const float*)d_in[5];
    const float* Whh1 = (const float*)d_in[6];
    const float* bih1 = (const float*)d_in[7];
    const float* bhh1 = (const float*)d_in[8];
    const float* Wfc  = (const float*)d_in[9];
    const float* bfc  = (const float*)d_in[10];
    float* out = (float*)d_out;

    char* ws = (char*)d_ws;
    size_t off = 0;
    auto alloc = [&](size_t bytes) -> void* {
        void* p = ws + off;
        off += (bytes + 255) & ~(size_t)255;
        return p;
    };
    const size_t MTD = (size_t)64 * 512 * 512;
    f16* xtm    = (f16*)alloc(MTD * 2);           // x, flatm-major
    f16* h0tm   = (f16*)alloc(MTD * 2);           // h0, flatm-major
    f16* xpk    = (f16*)alloc(MTD * 2);           // xproj, raw fragment layout
    f16* wih016 = (f16*)alloc((size_t)512 * 512 * 2);
    f16* wih116 = (f16*)alloc((size_t)512 * 512 * 2);
    f16* wpk0   = (f16*)alloc((size_t)512 * 512 * 2);
    f16* wpk1   = (f16*)alloc((size_t)512 * 512 * 2);
    float* bs0 = (float*)alloc(512 * 4);
    float* bs1 = (float*)alloc(512 * 4);
    f16* h1last = (f16*)alloc((size_t)64 * 512 * 2);

    // prep
    cvt_x_tm<<<2048, 256, 0, stream>>>(x, xtm, (int)(MTD / 4));
    cvt_kernel<<<256, 256, 0, stream>>>(Wih0, wih016, 512 * 512 / 4);
    cvt_kernel<<<256, 256, 0, stream>>>(Wih1, wih116, 512 * 512 / 4);
    bsum_kernel<<<1, 512, 0, stream>>>(bih0, bhh0, bs0);
    bsum_kernel<<<1, 512, 0, stream>>>(bih1, bhh1, bs1);
    packw_frag<<<1024, 256, 0, stream>>>(Whh0, wpk0);
    packw_frag<<<1024, 256, 0, stream>>>(Whh1, wpk1);

    // layer 0
    gemm_frag<<<1024, 256, 0, stream>>>(wih016, xtm, bs0, xpk);
    rnn_mfma<<<4, 512, 0, stream>>>(xpk, wpk0, h0tm, nullptr, 1);
    // layer 1
    gemm_frag<<<1024, 256, 0, stream>>>(wih116, h0tm, bs1, xpk);
    rnn_mfma<<<4, 512, 0, stream>>>(xpk, wpk1, nullptr, h1last, 0);
    // head
    fc_kernel<<<64, 512, 0, stream>>>(h1last, Wfc, bfc, out);
}

// Round 11
// 1355.120 us; speedup vs baseline: 2.9259x; 2.9259x over previous
//
#include <hip/hip_runtime.h>
#include <cstdint>
#include <cstddef>

typedef _Float16 f16;
typedef _Float16 half2_t __attribute__((ext_vector_type(2)));
typedef _Float16 half4_t __attribute__((ext_vector_type(4)));
typedef _Float16 half8_t __attribute__((ext_vector_type(8)));
typedef float floatx4 __attribute__((ext_vector_type(4)));

__device__ __forceinline__ float fdot2u(uint32_t w, uint32_t h, float acc) {
#if __has_builtin(__builtin_amdgcn_fdot2)
    return __builtin_amdgcn_fdot2(__builtin_bit_cast(half2_t, w),
                                  __builtin_bit_cast(half2_t, h), acc, false);
#else
    half2_t a = __builtin_bit_cast(half2_t, w);
    half2_t b = __builtin_bit_cast(half2_t, h);
    return acc + (float)a[0] * (float)b[0] + (float)a[1] * (float)b[1];
#endif
}

// relaxed spin (no per-iteration cache invalidate); pair with one __threadfence after
__device__ __forceinline__ void spin_ge(int* f, int v) {
    while (__hip_atomic_load(f, __ATOMIC_RELAXED, __HIP_MEMORY_SCOPE_AGENT) < v)
        __builtin_amdgcn_s_sleep(16);
}

// ---------------- fp32 -> f16 conversion ----------------
__global__ void cvt_kernel(const float* __restrict__ in, f16* __restrict__ out, int n4) {
    int i = blockIdx.x * blockDim.x + threadIdx.x;
    int stride = gridDim.x * blockDim.x;
    const float4* in4 = (const float4*)in;
    for (; i < n4; i += stride) {
        float4 v = in4[i];
        half4_t h = {(f16)v.x, (f16)v.y, (f16)v.z, (f16)v.w};
        *(half4_t*)&out[(size_t)i * 4] = h;
    }
}

// ---------------- bias sum ----------------
__global__ void bsum_kernel(const float* __restrict__ a, const float* __restrict__ b,
                            float* __restrict__ o) {
    int i = threadIdx.x;
    o[i] = a[i] + b[i];
}

// ---------------- pack W (round-7/8 layout, proven) ----------------
// 512 threads. tid: w = tid>>6, jsub = (tid>>3)&7, kg = tid&7.
// j = w*64 + jsub*8 + r; k = kg*64 + c*8 + 2q (+par).  idx = c*32 + r*4 + q.
// idx < 224 (c<7): registers, wp[idx*512 + tid];  c == 7: LDS, wp[224*512 + (r*512+tid)*4 + q].
__global__ void pack_whh(const float* __restrict__ W, uint32_t* __restrict__ wp) {
    int id = blockIdx.x * 256 + threadIdx.x;   // 131072 pairs
    int j = id >> 8;
    int kp = id & 255;
    int k = kp * 2;
    int w = j >> 6, jsub = (j >> 3) & 7, r = j & 7;
    int kg = k >> 6, c = (k >> 3) & 7, q = (k >> 1) & 3;
    int tid = w * 64 + jsub * 8 + kg;
    int idx = c * 32 + r * 4 + q;
    uint32_t lo = (uint32_t)__builtin_bit_cast(uint16_t, (f16)W[(size_t)j * 512 + k]);
    uint32_t hi = (uint32_t)__builtin_bit_cast(uint16_t, (f16)W[(size_t)j * 512 + k + 1]);
    size_t off;
    if (idx < 224) off = (size_t)idx * 512 + tid;
    else           off = (size_t)224 * 512 + ((size_t)(r * 512 + tid)) * 4 + q;
    wp[off] = (hi << 16) | lo;
}

// ---------------- xproj GEMM for layer 0 (proven) ----------------
__global__ __launch_bounds__(256) void gemm_xp(const f16* __restrict__ A,
                                               const f16* __restrict__ Bw,
                                               const float* __restrict__ bias,
                                               f16* __restrict__ C) {
    const int bn = blockIdx.x & 3;
    const int bm = blockIdx.x >> 2;
    const int tid = threadIdx.x;
    const int w = tid >> 6, l = tid & 63;
    const int wr = w >> 1, wc = w & 1;
    __shared__ f16 As[128 * 32];
    __shared__ f16 Bs[128 * 32];
    floatx4 acc[4][4] = {};
    const int lr = l & 15, lk = (l >> 4) * 8;
    for (int kk = 0; kk < 512; kk += 32) {
        __syncthreads();
        uint4 av[2], bv[2];
#pragma unroll
        for (int s = 0; s < 2; ++s) {
            int chunk = tid + s * 256;
            int row = chunk >> 2;
            int colh = (chunk & 3) * 8;
            av[s] = *(const uint4*)&A[((size_t)(bm * 128 + row)) * 512 + kk + colh];
            bv[s] = *(const uint4*)&Bw[((size_t)(bn * 128 + row)) * 512 + kk + colh];
        }
#pragma unroll
        for (int s = 0; s < 2; ++s) {
            int chunk = tid + s * 256;
            *(uint4*)&As[chunk * 8] = av[s];
            *(uint4*)&Bs[chunk * 8] = bv[s];
        }
        __syncthreads();
        half8_t af[4], bf[4];
#pragma unroll
        for (int m = 0; m < 4; ++m)
            af[m] = *(const half8_t*)&As[(wr * 64 + m * 16 + lr) * 32 + lk];
#pragma unroll
        for (int n = 0; n < 4; ++n)
            bf[n] = *(const half8_t*)&Bs[(wc * 64 + n * 16 + lr) * 32 + lk];
#pragma unroll
        for (int m = 0; m < 4; ++m)
#pragma unroll
            for (int n = 0; n < 4; ++n)
                acc[m][n] = __builtin_amdgcn_mfma_f32_16x16x32_f16(af[m], bf[n], acc[m][n], 0, 0, 0);
    }
    float bz[4];
#pragma unroll
    for (int n = 0; n < 4; ++n) bz[n] = bias[bn * 128 + wc * 64 + n * 16 + lr];
    const int lq = l >> 4;
#pragma unroll
    for (int m = 0; m < 4; ++m)
#pragma unroll
        for (int n = 0; n < 4; ++n)
#pragma unroll
            for (int e = 0; e < 4; ++e) {
                int row = bm * 128 + wr * 64 + m * 16 + lq * 4 + e;
                int col = bn * 128 + wc * 64 + n * 16 + lr;
                C[(size_t)row * 512 + col] = (f16)(acc[m][n][e] + bz[n]);
            }
}

// ---------------- fused 3-stage pipeline ----------------
#define FOR_Q(M, c, r) M(c, r, 0) M(c, r, 1) M(c, r, 2) M(c, r, 3)
#define FOR_R8(M, c) FOR_Q(M, c, 0) FOR_Q(M, c, 1) FOR_Q(M, c, 2) FOR_Q(M, c, 3) \
                     FOR_Q(M, c, 4) FOR_Q(M, c, 5) FOR_Q(M, c, 6) FOR_Q(M, c, 7)
#define FOR_ALL(M) FOR_R8(M, 0) FOR_R8(M, 1) FOR_R8(M, 2) FOR_R8(M, 3) \
                   FOR_R8(M, 4) FOR_R8(M, 5) FOR_R8(M, 6)

#define DECLW(c, r, q) uint32_t W_##c##_##r##_##q;
#define LOADW(c, r, q) W_##c##_##r##_##q = wpb[(size_t)(((c)*32 + (r)*4 + (q)) * 512) + tid];
#define DOTQ(c, r, q) a##r = fdot2u(W_##c##_##r##_##q, hq##q, a##r);

#define CHUNK(c)                                                   \
    {                                                              \
        uint4 hv = *(const uint4*)(hrow + (c) * 4);                \
        uint32_t hq0 = hv.x, hq1 = hv.y, hq2 = hv.z, hq3 = hv.w;   \
        FOR_R8(DOTQ, c)                                            \
    }

#define LROW(r)                                                    \
    {                                                              \
        uint4 wv = *(const uint4*)&wlds[((r) * 512 + tid) * 4];    \
        a##r = fdot2u(wv.x, hq0, a##r);                            \
        a##r = fdot2u(wv.y, hq1, a##r);                            \
        a##r = fdot2u(wv.z, hq2, a##r);                            \
        a##r = fdot2u(wv.w, hq3, a##r);                            \
    }

#define CHUNKL                                                     \
    {                                                              \
        uint4 hv = *(const uint4*)(hrow + 7 * 4);                  \
        uint32_t hq0 = hv.x, hq1 = hv.y, hq2 = hv.z, hq3 = hv.w;   \
        LROW(0) LROW(1) LROW(2) LROW(3)                            \
        LROW(4) LROW(5) LROW(6) LROW(7)                            \
    }

#define TREE8                                                                 \
    float b0 = (m0 ? a1 : a0) + __shfl_xor(m0 ? a0 : a1, 1);                  \
    float b1 = (m0 ? a3 : a2) + __shfl_xor(m0 ? a2 : a3, 1);                  \
    float b2 = (m0 ? a5 : a4) + __shfl_xor(m0 ? a4 : a5, 1);                  \
    float b3 = (m0 ? a7 : a6) + __shfl_xor(m0 ? a6 : a7, 1);                  \
    float c0 = (m1 ? b1 : b0) + __shfl_xor(m1 ? b0 : b1, 2);                  \
    float c1 = (m1 ? b3 : b2) + __shfl_xor(m1 ? b2 : b3, 2);                  \
    float d0 = (m2 ? c1 : c0) + __shfl_xor(m2 ? c0 : c1, 4);

#define HB_STRIDE 72    // 64 f16 + 8 pad per k-group: bank-conflict-free uint4 reads
#define XROW 576        // xin row stride in f16 = 8 k-groups x 72

// 192 blocks: [0,64) rnn layer-0; [64,128) proj xp1 = Wih1*h0 + bs1 (chunk-parallel);
// [128,192) rnn layer-1.  flag = number of completed 16-step chunks (memset 0 per launch).
__global__ __launch_bounds__(512)
__attribute__((amdgpu_waves_per_eu(2, 2)))
void fused3(const f16* __restrict__ xp0, const uint32_t* __restrict__ wp0,
            const uint32_t* __restrict__ wpih1, const uint32_t* __restrict__ wp1,
            const float* __restrict__ bs1,
            f16* __restrict__ h0seq, f16* __restrict__ xp1seq,
            f16* __restrict__ h1last,
            int* __restrict__ flag1, int* __restrict__ flag2) {
    const int stage = blockIdx.x >> 6;
    const int row = blockIdx.x & 63;
    const int tid = threadIdx.x;
    const int kg = tid & 7;
    __shared__ alignas(16) f16 hbuf[2][8 * HB_STRIDE];
    __shared__ uint32_t wlds[8 * 512 * 4];            // 64 KB
    __shared__ alignas(16) f16 xin[2][16 * XROW];     // 36 KB double-buffered input chunks

    const uint32_t* wpb = (stage == 0) ? wp0 : (stage == 1) ? wpih1 : wp1;
    const f16* inbase = (stage == 0) ? xp0 + (size_t)row * 262144
                       : (stage == 1) ? h0seq + (size_t)row * 262144
                                      : xp1seq + (size_t)row * 262144;
    f16* outbase = (stage == 0) ? h0seq + (size_t)row * 262144
                  : (stage == 1) ? xp1seq + (size_t)row * 262144
                                 : h1last + (size_t)row * 512;
    int* flIn  = (stage == 1) ? flag1 + row : (stage == 2) ? flag2 + row : nullptr;
    int* flOut = (stage == 0) ? flag1 + row : (stage == 1) ? flag2 + row : nullptr;

    // stage 16-step input chunk g into padded xin[g&1]: 2 uint4 loads + 2 b128 LDS writes.
    // slot s: row rw = s>>6, pos = s&63 (16B units); global f16 idx (g*16+rw)*512 + pos*8
    // -> xin f16 idx rw*XROW + (pos>>3)*72 + (pos&7)*8.  (d -> (d>>6)*72 + (d&63))
    auto stageChunk = [&](int g) {
#pragma unroll
        for (int s2 = 0; s2 < 2; ++s2) {
            int s = tid + s2 * 512;
            int rw = s >> 6, pos = s & 63;
            uint4 v = *(const uint4*)&inbase[(size_t)(g * 16 + rw) * 512 + pos * 8];
            *(uint4*)&xin[g & 1][rw * XROW + (pos >> 3) * 72 + (pos & 7) * 8] = v;
        }
    };

    FOR_ALL(DECLW)
    FOR_ALL(LOADW)
#pragma unroll
    for (int i = 0; i < 8; ++i) {
        uint4 v = *(const uint4*)&wpb[(size_t)224 * 512 + (size_t)(i * 512 + tid) * 4];
        *(uint4*)&wlds[(i * 512 + tid) * 4] = v;
    }
    for (int i = tid; i < 2 * 8 * HB_STRIDE; i += 512) ((f16*)hbuf)[i] = (f16)0.f;
    float bsv = (stage == 1) ? bs1[tid] : 0.f;

    if (flIn) { spin_ge(flIn, 1); __threadfence(); }   // chunk 0 ready
    stageChunk(0);
    __syncthreads();

    const bool m0 = (tid & 1), m1 = (tid & 2), m2 = (tid & 4);
    const int hwpos = (tid >> 6) * HB_STRIDE + (tid & 63);

    if (stage == 1) {
        // ---- projection: no recurrence -> barrier-free within each 16-step chunk ----
        for (int c = 0; c < 32; ++c) {
            for (int lt = 0; lt < 16; ++lt) {
                if (lt == 12 && c < 31) {
                    spin_ge(flIn, c + 2); __threadfence();
                    stageChunk(c + 1);                 // other buffer; drift-safe (chunk barrier)
                }
                float a0 = 0.f, a1 = 0.f, a2 = 0.f, a3 = 0.f;
                float a4 = 0.f, a5 = 0.f, a6 = 0.f, a7 = 0.f;
                const uint32_t* hrow = (const uint32_t*)&xin[c & 1][lt * XROW + kg * 72];
                CHUNKL
                CHUNK(0) CHUNK(1) CHUNK(2) CHUNK(3) CHUNK(4) CHUNK(5) CHUNK(6)
                TREE8
                outbase[(size_t)(c * 16 + lt) * 512 + tid] = (f16)(d0 + bsv);
            }
            __syncthreads();                           // drains stores + LDS writes
            if (tid == 0) {
                __threadfence();
                __hip_atomic_store(flOut, c + 1, __ATOMIC_RELAXED, __HIP_MEMORY_SCOPE_AGENT);
            }
        }
    } else {
        // ---- recurrence stages (R8 core): one barrier per step ----
        int p = 0;
        for (int t = 0; t < 512; ++t) {
            const int c = t >> 4, lt = t & 15;
            if (lt == 12 && c < 31) {
                if (flIn) { spin_ge(flIn, c + 2); __threadfence(); }
                stageChunk(c + 1);
            }
            float xpv = (float)xin[c & 1][lt * XROW + (tid >> 6) * 72 + (tid & 63)];

            float a0 = 0.f, a1 = 0.f, a2 = 0.f, a3 = 0.f;
            float a4 = 0.f, a5 = 0.f, a6 = 0.f, a7 = 0.f;
            const uint32_t* hrow = (const uint32_t*)&hbuf[p][kg * HB_STRIDE];
            CHUNKL
            CHUNK(0) CHUNK(1) CHUNK(2) CHUNK(3) CHUNK(4) CHUNK(5) CHUNK(6)
            TREE8
            float s = d0 + xpv;
            float e = __expf(2.0f * s);
            f16 hh = (f16)(1.0f - 2.0f / (1.0f + e));
            hbuf[p ^ 1][hwpos] = hh;
            if (stage == 0) outbase[(size_t)t * 512 + tid] = hh;
            else if (t == 511) outbase[tid] = hh;
            __syncthreads();                           // drains global stores too
            if (stage == 0 && lt == 15 && tid == 0) {
                __threadfence();
                __hip_atomic_store(flOut, c + 1, __ATOMIC_RELAXED, __HIP_MEMORY_SCOPE_AGENT);
            }
            p ^= 1;
        }
    }
}

// ---------------- final FC ----------------
__global__ __launch_bounds__(512) void fc_kernel(const f16* __restrict__ h1,
                                                 const float* __restrict__ Wfc,
                                                 const float* __restrict__ bfc,
                                                 float* __restrict__ out) {
    int b = blockIdx.x, tid = threadIdx.x;
    __shared__ float red[8];
    float v = (float)h1[(size_t)b * 512 + tid] * Wfc[tid];
#pragma unroll
    for (int off = 32; off > 0; off >>= 1) v += __shfl_down(v, off, 64);
    if ((tid & 63) == 0) red[tid >> 6] = v;
    __syncthreads();
    if (tid == 0) {
        float s = bfc[0];
#pragma unroll
        for (int g = 0; g < 8; ++g) s += red[g];
        out[b] = s;
    }
}

extern "C" void kernel_launch(void* const* d_in, const int* in_sizes, int n_in,
                              void* d_out, int out_size, void* d_ws, size_t ws_size,
                              hipStream_t stream) {
    const float* x    = (const float*)d_in[0];
    const float* Wih0 = (const float*)d_in[1];
    const float* Whh0 = (const float*)d_in[2];
    const float* bih0 = (const float*)d_in[3];
    const float* bhh0 = (const float*)d_in[4];
    const float* Wih1 = (const float*)d_in[5];
    const float* Whh1 = (const float*)d_in[6];
    const float* bih1 = (const float*)d_in[7];
    const float* bhh1 = (const float*)d_in[8];
    const float* Wfc  = (const float*)d_in[9];
    const float* bfc  = (const float*)d_in[10];
    float* out = (float*)d_out;

    char* ws = (char*)d_ws;
    size_t off = 0;
    auto alloc = [&](size_t bytes) -> void* {
        void* p = ws + off;
        off += (bytes + 255) & ~(size_t)255;
        return p;
    };
    const size_t MTD = (size_t)64 * 512 * 512;
    f16* x16    = (f16*)alloc(MTD * 2);
    f16* h016   = (f16*)alloc(MTD * 2);
    f16* xpb    = (f16*)alloc(MTD * 2);
    f16* xp1b   = (f16*)alloc(MTD * 2);
    f16* wih016 = (f16*)alloc((size_t)512 * 512 * 2);
    uint32_t* wp0   = (uint32_t*)alloc((size_t)131072 * 4);
    uint32_t* wp1   = (uint32_t*)alloc((size_t)131072 * 4);
    uint32_t* wpih1 = (uint32_t*)alloc((size_t)131072 * 4);
    float* bs0 = (float*)alloc(512 * 4);
    float* bs1 = (float*)alloc(512 * 4);
    f16* h1last = (f16*)alloc((size_t)64 * 512 * 2);
    int* flags = (int*)alloc(128 * 4);   // flag1[64] + flag2[64]

    // prep
    cvt_kernel<<<2048, 256, 0, stream>>>(x, x16, (int)(MTD / 4));
    cvt_kernel<<<256, 256, 0, stream>>>(Wih0, wih016, 512 * 512 / 4);
    bsum_kernel<<<1, 512, 0, stream>>>(bih0, bhh0, bs0);
    bsum_kernel<<<1, 512, 0, stream>>>(bih1, bhh1, bs1);
    pack_whh<<<512, 256, 0, stream>>>(Whh0, wp0);
    pack_whh<<<512, 256, 0, stream>>>(Whh1, wp1);
    pack_whh<<<512, 256, 0, stream>>>(Wih1, wpih1);
    hipMemsetAsync(flags, 0, 128 * 4, stream);

    // layer-0 xproj GEMM, then the fused 3-stage pipeline, then the head
    gemm_xp<<<1024, 256, 0, stream>>>(x16, wih016, bs0, xpb);
    fused3<<<192, 512, 0, stream>>>(xpb, wp0, wpih1, wp1, bs1,
                                    h016, xp1b, h1last, flags, flags + 64);
    fc_kernel<<<64, 512, 0, stream>>>(h1last, Wfc, bfc, out);
}